// Round 5
// baseline (260.750 us; speedup 1.0000x reference)
//
#include <hip/hip_runtime.h>

// Net_18966575579675: 722 tiny MLPs (11->10->10->6), B=8192, fp32.
// R9 = R8 resubmitted (R8 bench died on container acquire, not on the
// kernel; audit found no hang/OOB). Theory unchanged:
// R4-R7 falsified grid, LDS size, barrier semantics, spills and occupancy
// as limiters (all ~118-130us). Residual suspects are per-wave invariants:
// ONE serialized s_load->drain->FMA weight stream (SMEM lgkmcnt retires
// out-of-order -> every use cluster fully drains) and 4 barrier rendezvous
// per chunk phase-locking the block.
// Changes vs R7: each wave processes TWO nets (fused chunk pair) x TWO
// rows -> two independent scalar streams + 2x FMA ILP hide each other's
// drains within the wave; barriers -> 1 pair per 8 nets; output runs per
// row grow to 48 contiguous floats (192B, full lines); camera ds_reads
// shared by both nets. Block = 128 rows x 8 nets, obuf [128][49] (odd
// stride), ~30KB LDS, ~110 live VGPRs, `unroll 1` on the pair loop.

#define NN 722
#define CAMD 10
#define HD 10
#define LODD 6
#define ROWF (NN * LODD)       // 4332 floats per output row
#define ROWS 128               // batch rows per block (2 per lane)
#define NPAIRS 91              // ceil(181 chunks / 2); pair p = nets 8p..8p+7
#define PPB 2                  // pairs per block
#define GY 46                  // ceil(91/2)
#define LSTRIDE 49             // 48 floats + 1 pad (odd -> conflict-free)

// LDS-only barrier: order ds ops across waves WITHOUT draining vmcnt
// (global stores / prefetch loads stay in flight).
__device__ __forceinline__ void lds_barrier() {
    asm volatile("s_waitcnt lgkmcnt(0)" ::: "memory");
    __builtin_amdgcn_s_barrier();
}

__global__ __launch_bounds__(256) void Net_18966575579675_kernel(
    const float* __restrict__ prior, const float* __restrict__ camera,
    const float* __restrict__ W1, const float* __restrict__ b1,
    const float* __restrict__ W2, const float* __restrict__ b2,
    const float* __restrict__ W3, const float* __restrict__ b3,
    float* __restrict__ out)
{
    const int tid  = threadIdx.x;
    const int lane = tid & 63;
    const int wave = __builtin_amdgcn_readfirstlane(tid >> 6);
    const int b0   = blockIdx.x * ROWS;

    const int p_begin = blockIdx.y * PPB;
    const int p_end   = (p_begin + PPB < NPAIRS) ? (p_begin + PPB) : NPAIRS;

    __shared__ float cam_lds[CAMD][ROWS];    // 5120 B
    __shared__ float obuf[ROWS * LSTRIDE];   // 25088 B

    // stage camera transposed (threads 0..127 own one row each)
    if (tid < ROWS) {
        const float2* c2 = (const float2*)(camera + (size_t)(b0 + tid) * CAMD);
#pragma unroll
        for (int i = 0; i < CAMD / 2; ++i) {
            float2 v = c2[i];
            cam_lds[2 * i][tid]     = v.x;
            cam_lds[2 * i + 1][tid] = v.y;
        }
    }

    // prior prefetch for the first pair (clamped; clamped lanes unused)
    float prA0, prA1, prB0, prB1;
    {
        const int na = p_begin * 8 + wave;
        const int nb = p_begin * 8 + 4 + wave;
        const int ca = na < NN ? na : NN - 1;
        const int cb = nb < NN ? nb : NN - 1;
        prA0 = prior[(size_t)(b0 + lane) * NN + ca];
        prA1 = prior[(size_t)(b0 + 64 + lane) * NN + ca];
        prB0 = prior[(size_t)(b0 + lane) * NN + cb];
        prB1 = prior[(size_t)(b0 + 64 + lane) * NN + cb];
    }

    lds_barrier();   // camera visible

#pragma unroll 1
    for (int p = p_begin; p < p_end; ++p) {
        if (8 * p >= NN) break;                 // wholly-invalid pair (uniform)

        const int naRaw = 8 * p + wave;         // chunk A net
        const int nbRaw = 8 * p + 4 + wave;     // chunk B net
        const bool actA = naRaw < NN;
        const bool actB = nbRaw < NN;
        const int nA = actA ? naRaw : NN - 1;
        const int nB = actB ? nbRaw : NN - 1;

        const float* __restrict__ w1A = W1 + (size_t)nA * (CAMD + 1) * HD;
        const float* __restrict__ w1B = W1 + (size_t)nB * (CAMD + 1) * HD;
        const float* __restrict__ p1A = b1 + (size_t)nA * HD;
        const float* __restrict__ p1B = b1 + (size_t)nB * HD;
        const float* __restrict__ w2A = W2 + (size_t)nA * HD * HD;
        const float* __restrict__ w2B = W2 + (size_t)nB * HD * HD;
        const float* __restrict__ p2A = b2 + (size_t)nA * HD;
        const float* __restrict__ p2B = b2 + (size_t)nB * HD;
        const float* __restrict__ w3A = W3 + (size_t)nA * HD * LODD;
        const float* __restrict__ w3B = W3 + (size_t)nB * HD * LODD;
        const float* __restrict__ p3A = b3 + (size_t)nA * LODD;
        const float* __restrict__ p3B = b3 + (size_t)nB * LODD;

        // prefetch next pair's prior (stores/loads never drained by barriers)
        float nxA0 = prA0, nxA1 = prA1, nxB0 = prB0, nxB1 = prB1;
        if (p + 1 < p_end && 8 * (p + 1) < NN) {
            const int na2 = 8 * (p + 1) + wave;
            const int nb2 = 8 * (p + 1) + 4 + wave;
            const int ca2 = na2 < NN ? na2 : NN - 1;
            const int cb2 = nb2 < NN ? nb2 : NN - 1;
            nxA0 = prior[(size_t)(b0 + lane) * NN + ca2];
            nxA1 = prior[(size_t)(b0 + 64 + lane) * NN + ca2];
            nxB0 = prior[(size_t)(b0 + lane) * NN + cb2];
            nxB1 = prior[(size_t)(b0 + 64 + lane) * NN + cb2];
        }

        // ---- layer 1: two nets x two rows, interleaved ----
        float h1A[2][HD], h1B[2][HD];
#pragma unroll
        for (int j = 0; j < HD; ++j) {
            const float wA = w1A[j], bA = p1A[j];
            const float wB = w1B[j], bB = p1B[j];
            h1A[0][j] = fmaf(prA0, wA, bA);
            h1A[1][j] = fmaf(prA1, wA, bA);
            h1B[0][j] = fmaf(prB0, wB, bB);
            h1B[1][j] = fmaf(prB1, wB, bB);
        }
#pragma unroll
        for (int i = 0; i < CAMD; ++i) {
            const float c0 = cam_lds[i][lane];        // shared by both nets
            const float c1 = cam_lds[i][64 + lane];
#pragma unroll
            for (int j = 0; j < HD; ++j) {
                const float wA = w1A[(i + 1) * HD + j];
                const float wB = w1B[(i + 1) * HD + j];
                h1A[0][j] = fmaf(c0, wA, h1A[0][j]);
                h1A[1][j] = fmaf(c1, wA, h1A[1][j]);
                h1B[0][j] = fmaf(c0, wB, h1B[0][j]);
                h1B[1][j] = fmaf(c1, wB, h1B[1][j]);
            }
        }
#pragma unroll
        for (int j = 0; j < HD; ++j) {
            h1A[0][j] = fmaxf(h1A[0][j], 0.0f);
            h1A[1][j] = fmaxf(h1A[1][j], 0.0f);
            h1B[0][j] = fmaxf(h1B[0][j], 0.0f);
            h1B[1][j] = fmaxf(h1B[1][j], 0.0f);
        }

        // ---- layer 2 ----
        float h2A[2][HD], h2B[2][HD];
#pragma unroll
        for (int k = 0; k < HD; ++k) {
            const float bA = p2A[k], bB = p2B[k];
            h2A[0][k] = bA; h2A[1][k] = bA;
            h2B[0][k] = bB; h2B[1][k] = bB;
        }
#pragma unroll
        for (int j = 0; j < HD; ++j) {
#pragma unroll
            for (int k = 0; k < HD; ++k) {
                const float wA = w2A[j * HD + k];
                const float wB = w2B[j * HD + k];
                h2A[0][k] = fmaf(h1A[0][j], wA, h2A[0][k]);
                h2A[1][k] = fmaf(h1A[1][j], wA, h2A[1][k]);
                h2B[0][k] = fmaf(h1B[0][j], wB, h2B[0][k]);
                h2B[1][k] = fmaf(h1B[1][j], wB, h2B[1][k]);
            }
        }
#pragma unroll
        for (int k = 0; k < HD; ++k) {
            h2A[0][k] = fmaxf(h2A[0][k], 0.0f);
            h2A[1][k] = fmaxf(h2A[1][k], 0.0f);
            h2B[0][k] = fmaxf(h2B[0][k], 0.0f);
            h2B[1][k] = fmaxf(h2B[1][k], 0.0f);
        }

        // ---- layer 3 ----
        float oA[2][LODD], oB[2][LODD];
#pragma unroll
        for (int m = 0; m < LODD; ++m) {
            const float bA = p3A[m], bB = p3B[m];
            oA[0][m] = bA; oA[1][m] = bA;
            oB[0][m] = bB; oB[1][m] = bB;
        }
#pragma unroll
        for (int j = 0; j < HD; ++j) {
#pragma unroll
            for (int m = 0; m < LODD; ++m) {
                const float wA = w3A[j * LODD + m];
                const float wB = w3B[j * LODD + m];
                oA[0][m] = fmaf(h2A[0][j], wA, oA[0][m]);
                oA[1][m] = fmaf(h2A[1][j], wA, oA[1][m]);
                oB[0][m] = fmaf(h2B[0][j], wB, oB[0][m]);
                oB[1][m] = fmaf(h2B[1][j], wB, oB[1][m]);
            }
        }

        lds_barrier();   // previous iteration's flush reads complete everywhere

        // stash: row = s*64+lane; net A at cols [wave*6), net B at 24+wave*6
        if (actA) {
#pragma unroll
            for (int s = 0; s < 2; ++s)
#pragma unroll
                for (int m = 0; m < LODD; ++m)
                    obuf[(s * 64 + lane) * LSTRIDE + wave * LODD + m] = oA[s][m];
        }
        if (actB) {
#pragma unroll
            for (int s = 0; s < 2; ++s)
#pragma unroll
                for (int m = 0; m < LODD; ++m)
                    obuf[(s * 64 + lane) * LSTRIDE + 24 + wave * LODD + m] = oB[s][m];
        }

        lds_barrier();   // stash visible

        // flush: 48 (or 12) floats per row, 128 rows; stores left in flight
        const int rem = NN - 8 * p;
        if (rem >= 8) {
            // nq = 12 float4 per row
            for (int f = tid; f < ROWS * 12; f += 256) {
                const int row  = f / 12;            // compile-time divide
                const int colq = f - row * 12;
                const float* sp = obuf + row * LSTRIDE + colq * 4;
                float4 v = make_float4(sp[0], sp[1], sp[2], sp[3]);
                *(float4*)(out + (size_t)(b0 + row) * ROWF + p * 48 + colq * 4) = v;
            }
        } else {
            // last pair: rem = 2 nets -> nq = 3
            for (int f = tid; f < ROWS * 3; f += 256) {
                const int row  = f / 3;
                const int colq = f - row * 3;
                const float* sp = obuf + row * LSTRIDE + colq * 4;
                float4 v = make_float4(sp[0], sp[1], sp[2], sp[3]);
                *(float4*)(out + (size_t)(b0 + row) * ROWF + p * 48 + colq * 4) = v;
            }
        }

        prA0 = nxA0; prA1 = nxA1; prB0 = nxB0; prB1 = nxB1;
    }
}

extern "C" void kernel_launch(void* const* d_in, const int* in_sizes, int n_in,
                              void* d_out, int out_size, void* d_ws, size_t ws_size,
                              hipStream_t stream) {
    const float* prior  = (const float*)d_in[0];
    const float* camera = (const float*)d_in[1];
    const float* W1     = (const float*)d_in[2];
    const float* b1     = (const float*)d_in[3];
    const float* W2     = (const float*)d_in[4];
    const float* b2     = (const float*)d_in[5];
    const float* W3     = (const float*)d_in[6];
    const float* b3     = (const float*)d_in[7];
    float* out = (float*)d_out;

    dim3 grid(8192 / ROWS, GY);   // 64 x 46 = 2944 blocks
    dim3 block(256);
    Net_18966575579675_kernel<<<grid, block, 0, stream>>>(
        prior, camera, W1, b1, W2, b2, W3, b3, out);
}

// Round 7
// 241.999 us; speedup vs baseline: 1.0775x; 1.0775x over previous
//
#include <hip/hip_runtime.h>

// Net_18966575579675: 722 tiny MLPs (11->10->10->6), B=8192, fp32.
// R11 = R10 resubmitted (container acquire failed twice; audit found no
// hang/OOB/race — same infra signature as R8, which passed on identical
// resubmit as R9). Theory unchanged:
// R4-R9 falsified grid, LDS size, barrier drains, spills, occupancy and
// dual-stream ILP (compiler re-serialized it, VGPR=48). VALUBusy
// recalibrated = per-SIMD busy: R7 had only ~46us of issue in 119us ->
// ~73us of correlated stall. Last untouched invariant: wave-uniform
// s_load weight fetch. Per-block weight set (~10-19KB) misses the scalar
// K$ -> every load-use round = L2 latency, and SMEM retires OUT-OF-ORDER
// so each use forces a full lgkmcnt(0) drain; SGPR budget (112) keeps
// rounds short. The compiler cannot pipeline this (no counted wait for
// OoO SMEM). Fix: stage each chunk's 4 nets (1.4KB/net, rows padded to
// 16B) into a double-buffered LDS weight cache with coalesced vector
// loads; hot loop reads weights as broadcast ds_read_b128 (same address
// all lanes = conflict-free, IN-ORDER -> counted lgkmcnt, pipelined).
// No SMEM in the loop. Shell = R7: 256 rows, 4 rows/lane, 1 net/wave,
// cam in LDS, obuf half-flush, non-draining lds_barrier, prior prefetch.

#define NN 722
#define CAMD 10
#define HD 10
#define LODD 6
#define ROWF (NN * LODD)       // 4332 floats per output row
#define BT 256                 // batch rows per block (4 per lane)
#define NETS_PER_CHUNK 4       // one net per wave
#define NCHUNKS 181            // ceil(722/4); last chunk has 2 nets
#define CPG 2                  // chunks per y-group
#define NGROUPS 91             // 91*2 = 182 slots >= 181 chunks
#define LSTRIDE 25             // obuf: 24 floats + 1 pad
#define HROWS 128              // rows per flush pass

// LDS weight-cache layout per net (floats), rows padded for 16B alignment:
//  w1: 11 rows x 12  @ 0      (w1[i][j] at i*12+j)
//  w2: 10 rows x 12  @ 132
//  w3: 10 rows x 8   @ 252
//  b1: 10 @ 332   b2: 10 @ 344   b3: 6 @ 356   (all 16B-aligned)
#define NETSTRIDE 368
#define OFF_W2 132
#define OFF_W3 252
#define OFF_B1 332
#define OFF_B2 344
#define OFF_B3 356

// LDS-only barrier: order ds ops across waves WITHOUT draining vmcnt
// (global stores / prefetch loads stay in flight).
__device__ __forceinline__ void lds_barrier() {
    asm volatile("s_waitcnt lgkmcnt(0)" ::: "memory");
    __builtin_amdgcn_s_barrier();
}

// 10 consecutive LDS floats as b128+b128+b64 (base must be 16B-aligned)
#define LOAD10(dst, base) do {                                   \
    const float4 _a = *(const float4*)(base);                    \
    const float4 _b = *(const float4*)((base) + 4);              \
    const float2 _c = *(const float2*)((base) + 8);              \
    dst[0]=_a.x; dst[1]=_a.y; dst[2]=_a.z; dst[3]=_a.w;          \
    dst[4]=_b.x; dst[5]=_b.y; dst[6]=_b.z; dst[7]=_b.w;          \
    dst[8]=_c.x; dst[9]=_c.y; } while (0)

// 6 consecutive LDS floats as b128+b64 (base 16B-aligned)
#define LOAD6(dst, base) do {                                    \
    const float4 _a = *(const float4*)(base);                    \
    const float2 _c = *(const float2*)((base) + 4);              \
    dst[0]=_a.x; dst[1]=_a.y; dst[2]=_a.z; dst[3]=_a.w;          \
    dst[4]=_c.x; dst[5]=_c.y; } while (0)

__global__ __launch_bounds__(256, 4) void Net_18966575579675_kernel(
    const float* __restrict__ prior, const float* __restrict__ camera,
    const float* __restrict__ W1, const float* __restrict__ b1,
    const float* __restrict__ W2, const float* __restrict__ b2,
    const float* __restrict__ W3, const float* __restrict__ b3,
    float* __restrict__ out)
{
    const int tid  = threadIdx.x;
    const int lane = tid & 63;
    const int wave = __builtin_amdgcn_readfirstlane(tid >> 6);
    const int b0   = blockIdx.x * BT;

    const int c_begin = blockIdx.y * CPG;
    const int c_end   = (c_begin + CPG < NCHUNKS) ? (c_begin + CPG) : NCHUNKS;

    __shared__ float2 cam2[CAMD / 2][BT];                     // 10240 B
    __shared__ float  obuf[HROWS * LSTRIDE];                  // 12800 B
    __shared__ __align__(16) float wbuf[2][NETS_PER_CHUNK * NETSTRIDE]; // 11776 B

    // ---- stage camera transposed as float2 pairs (8B-aligned loads) ----
    {
        const float2* c2 = (const float2*)(camera + (size_t)(b0 + tid) * CAMD);
#pragma unroll
        for (int i = 0; i < CAMD / 2; ++i)
            cam2[i][tid] = c2[i];
    }

    // ---- cooperative weight staging: wave w stages net cc*4+w ----
    auto stage_now = [&](int cc) {
        const int ns = cc * NETS_PER_CHUNK + wave;
        if (ns < NN) {
            float* wd = &wbuf[cc & 1][wave * NETSTRIDE];
            const float* s1 = W1 + (size_t)ns * (CAMD + 1) * HD;   // 110
#pragma unroll
            for (int t0 = 0; t0 < 110; t0 += 64) {
                const int t = t0 + lane;
                if (t < 110) { const int i = t / 10, j = t - 10 * i; wd[i * 12 + j] = s1[t]; }
            }
            const float* s2 = W2 + (size_t)ns * HD * HD;           // 100
#pragma unroll
            for (int t0 = 0; t0 < 100; t0 += 64) {
                const int t = t0 + lane;
                if (t < 100) { const int j = t / 10, k = t - 10 * j; wd[OFF_W2 + j * 12 + k] = s2[t]; }
            }
            const float* s3 = W3 + (size_t)ns * HD * LODD;         // 60
            if (lane < 60) { const int j = lane / 6, m = lane - 6 * j; wd[OFF_W3 + j * 8 + m] = s3[lane]; }
            if (lane < 10)      wd[OFF_B1 + lane]      = b1[(size_t)ns * HD + lane];
            else if (lane < 20) wd[OFF_B2 + lane - 10] = b2[(size_t)ns * HD + lane - 10];
            else if (lane < 26) wd[OFF_B3 + lane - 20] = b3[(size_t)ns * LODD + lane - 20];
        }
    };

    stage_now(c_begin);   // prologue: first chunk's weights

    // ---- prior prefetch for first chunk (clamped; clamped lanes unused) ----
    float pr0, pr1, pr2, pr3;
    {
        const int n0 = c_begin * NETS_PER_CHUNK + wave;
        const int nc = n0 < NN ? n0 : NN - 1;
        pr0 = prior[(size_t)(b0 + 0 * 64 + lane) * NN + nc];
        pr1 = prior[(size_t)(b0 + 1 * 64 + lane) * NN + nc];
        pr2 = prior[(size_t)(b0 + 2 * 64 + lane) * NN + nc];
        pr3 = prior[(size_t)(b0 + 3 * 64 + lane) * NN + nc];
    }

    lds_barrier();   // camera + first weight chunk visible

#pragma unroll 1
    for (int c = c_begin; c < c_end; ++c) {
        const int n   = c * NETS_PER_CHUNK + wave;   // wave-uniform
        const bool act = (n < NN);

        // stage NEXT chunk's weights into the other buffer (each wave
        // stages and later reads its OWN region -> no cross-wave race)
        if (c + 1 < c_end) stage_now(c + 1);

        // prefetch next chunk's prior (never drained by lds_barrier)
        float nx0 = pr0, nx1 = pr1, nx2 = pr2, nx3 = pr3;
        if (c + 1 < c_end) {
            const int n1 = (c + 1) * NETS_PER_CHUNK + wave;
            const int nc = n1 < NN ? n1 : NN - 1;
            nx0 = prior[(size_t)(b0 + 0 * 64 + lane) * NN + nc];
            nx1 = prior[(size_t)(b0 + 1 * 64 + lane) * NN + nc];
            nx2 = prior[(size_t)(b0 + 2 * 64 + lane) * NN + nc];
            nx3 = prior[(size_t)(b0 + 3 * 64 + lane) * NN + nc];
        }

        float o[4][LODD];
        if (act) {
            const float* wb = &wbuf[c & 1][wave * NETSTRIDE];  // uniform base

            // ---- layer 1: h1 = relu(x @ W1 + b1), 4 rows concurrent ----
            float h1[4][HD];
            {
                float bv[10]; LOAD10(bv, wb + OFF_B1);
                float wv[10]; LOAD10(wv, wb);          // W1 row 0 (prior)
#pragma unroll
                for (int j = 0; j < HD; ++j) {
                    h1[0][j] = fmaf(pr0, wv[j], bv[j]);
                    h1[1][j] = fmaf(pr1, wv[j], bv[j]);
                    h1[2][j] = fmaf(pr2, wv[j], bv[j]);
                    h1[3][j] = fmaf(pr3, wv[j], bv[j]);
                }
            }
#pragma unroll
            for (int i2 = 0; i2 < CAMD / 2; ++i2) {
                const float2 c0 = cam2[i2][0 * 64 + lane];
                const float2 c1 = cam2[i2][1 * 64 + lane];
                const float2 c2v = cam2[i2][2 * 64 + lane];
                const float2 c3 = cam2[i2][3 * 64 + lane];
                float wa[10]; LOAD10(wa, wb + (2 * i2 + 1) * 12);
                float wc[10]; LOAD10(wc, wb + (2 * i2 + 2) * 12);
#pragma unroll
                for (int j = 0; j < HD; ++j) {
                    h1[0][j] = fmaf(c0.x, wa[j], h1[0][j]);
                    h1[1][j] = fmaf(c1.x, wa[j], h1[1][j]);
                    h1[2][j] = fmaf(c2v.x, wa[j], h1[2][j]);
                    h1[3][j] = fmaf(c3.x, wa[j], h1[3][j]);
                }
#pragma unroll
                for (int j = 0; j < HD; ++j) {
                    h1[0][j] = fmaf(c0.y, wc[j], h1[0][j]);
                    h1[1][j] = fmaf(c1.y, wc[j], h1[1][j]);
                    h1[2][j] = fmaf(c2v.y, wc[j], h1[2][j]);
                    h1[3][j] = fmaf(c3.y, wc[j], h1[3][j]);
                }
            }
#pragma unroll
            for (int s = 0; s < 4; ++s)
#pragma unroll
                for (int j = 0; j < HD; ++j)
                    h1[s][j] = fmaxf(h1[s][j], 0.0f);

            // ---- layer 2 ----
            float h2[4][HD];
            {
                float bv[10]; LOAD10(bv, wb + OFF_B2);
#pragma unroll
                for (int k = 0; k < HD; ++k) {
                    h2[0][k] = bv[k]; h2[1][k] = bv[k];
                    h2[2][k] = bv[k]; h2[3][k] = bv[k];
                }
            }
#pragma unroll
            for (int j = 0; j < HD; ++j) {
                float wv[10]; LOAD10(wv, wb + OFF_W2 + j * 12);
#pragma unroll
                for (int k = 0; k < HD; ++k) {
                    h2[0][k] = fmaf(h1[0][j], wv[k], h2[0][k]);
                    h2[1][k] = fmaf(h1[1][j], wv[k], h2[1][k]);
                    h2[2][k] = fmaf(h1[2][j], wv[k], h2[2][k]);
                    h2[3][k] = fmaf(h1[3][j], wv[k], h2[3][k]);
                }
            }
#pragma unroll
            for (int s = 0; s < 4; ++s)
#pragma unroll
                for (int k = 0; k < HD; ++k)
                    h2[s][k] = fmaxf(h2[s][k], 0.0f);

            // ---- layer 3 ----
            {
                float bv[6]; LOAD6(bv, wb + OFF_B3);
#pragma unroll
                for (int m = 0; m < LODD; ++m) {
                    o[0][m] = bv[m]; o[1][m] = bv[m];
                    o[2][m] = bv[m]; o[3][m] = bv[m];
                }
            }
#pragma unroll
            for (int j = 0; j < HD; ++j) {
                float wv[6]; LOAD6(wv, wb + OFF_W3 + j * 8);
#pragma unroll
                for (int m = 0; m < LODD; ++m) {
                    o[0][m] = fmaf(h2[0][j], wv[m], o[0][m]);
                    o[1][m] = fmaf(h2[1][j], wv[m], o[1][m]);
                    o[2][m] = fmaf(h2[2][j], wv[m], o[2][m]);
                    o[3][m] = fmaf(h2[3][j], wv[m], o[3][m]);
                }
            }
        }

        const int rem = NN - c * NETS_PER_CHUNK;
        const int nv  = rem < NETS_PER_CHUNK ? rem : NETS_PER_CHUNK;

        // two stash/flush passes over the half-size obuf
#pragma unroll
        for (int h = 0; h < 2; ++h) {
            if (act) {
#pragma unroll
                for (int ss = 0; ss < 2; ++ss) {
                    const int s = 2 * h + ss;
#pragma unroll
                    for (int m = 0; m < LODD; ++m)
                        obuf[(ss * 64 + lane) * LSTRIDE + wave * LODD + m] =
                            (s == 0) ? o[0][m] : (s == 1) ? o[1][m]
                          : (s == 2) ? o[2][m] : o[3][m];
                }
            }
            lds_barrier();   // stash visible

            if (nv == NETS_PER_CHUNK) {
                for (int f = tid; f < HROWS * 6; f += 256) {
                    const int row  = f / 6;              // compile-time div
                    const int colq = f - row * 6;
                    const float* sp = obuf + row * LSTRIDE + colq * 4;
                    float4 v = make_float4(sp[0], sp[1], sp[2], sp[3]);
                    *(float4*)(out + (size_t)(b0 + h * HROWS + row) * ROWF
                               + c * (NETS_PER_CHUNK * LODD) + colq * 4) = v;
                }
            } else {    // last chunk: nv = 2 -> nq = 3
                for (int f = tid; f < HROWS * 3; f += 256) {
                    const int row  = f / 3;
                    const int colq = f - row * 3;
                    const float* sp = obuf + row * LSTRIDE + colq * 4;
                    float4 v = make_float4(sp[0], sp[1], sp[2], sp[3]);
                    *(float4*)(out + (size_t)(b0 + h * HROWS + row) * ROWF
                               + c * (NETS_PER_CHUNK * LODD) + colq * 4) = v;
                }
            }
            lds_barrier();   // flush ds_reads done -> obuf reusable
        }

        pr0 = nx0; pr1 = nx1; pr2 = nx2; pr3 = nx3;
    }
}

extern "C" void kernel_launch(void* const* d_in, const int* in_sizes, int n_in,
                              void* d_out, int out_size, void* d_ws, size_t ws_size,
                              hipStream_t stream) {
    const float* prior  = (const float*)d_in[0];
    const float* camera = (const float*)d_in[1];
    const float* W1     = (const float*)d_in[2];
    const float* b1     = (const float*)d_in[3];
    const float* W2     = (const float*)d_in[4];
    const float* b2     = (const float*)d_in[5];
    const float* W3     = (const float*)d_in[6];
    const float* b3     = (const float*)d_in[7];
    float* out = (float*)d_out;

    dim3 grid(8192 / BT, NGROUPS);   // 32 x 91 = 2912 blocks
    dim3 block(256);
    Net_18966575579675_kernel<<<grid, block, 0, stream>>>(
        prior, camera, W1, b1, W2, b2, W3, b3, out);
}

// Round 8
// 215.423 us; speedup vs baseline: 1.2104x; 1.1234x over previous
//
#include <hip/hip_runtime.h>

// Net_18966575579675: 722 tiny MLPs (11->10->10->6), B=8192, fp32.
// R12: store-pattern attack. R4-R11 falsified grid, LDS size, barrier
// semantics, spills, occupancy, and weight-fetch path (s_load vs LDS) —
// all ~115-131us. The never-varied invariant is the flush: 96-B runs,
// misaligned (row stride 17328 B = 135.375 lines) -> every out line is an
// L2 miss + partial-line RMW; WRITE_SIZE swings 160->225 MB with
// occupancy (merge luck); achieved write BW pins at ~2 TB/s ~= dur.
// Fix: block = 256 rows x 16 nets (4 chunks), accumulate 96 floats/row
// in LDS, flush 384-B runs (~4x longer, ~2.3 full lines each). Barriers
// 2/chunk (was 4). Weights staged ONCE per block into wave-private LDS
// slots (no barrier needed). Keeps: LDS-broadcast weights, non-draining
// lds_barrier, prior prefetch, multi-row register core.
// LDS 48.4 KB -> 3 blocks/CU.

#define NN 722
#define CAMD 10
#define HD 10
#define LODD 6
#define ROWF (NN * LODD)       // 4332 floats per output row
#define NCHUNKS 181
#define NG 46                  // 4-chunk groups: 45 full + 1 tail(1 chunk)
#define OSTRIDE 97             // 96 cols + 1 pad (97 mod 32 = 1 -> stash conflict-free)

// per-net LDS weight slot (floats), rows padded for 16B alignment:
//  w1: 11 x 12 @ 0    w2: 10 x 12 @ 132   w3: 10 x 8 @ 252
//  b1: 10 @ 332       b2: 10 @ 344        b3: 6 @ 356
#define NETSTRIDE 368
#define OFF_W2 132
#define OFF_W3 252
#define OFF_B1 332
#define OFF_B2 344
#define OFF_B3 356

// LDS-only barrier: order ds ops across waves WITHOUT draining vmcnt
// (global stores / prefetch loads stay in flight).
__device__ __forceinline__ void lds_barrier() {
    asm volatile("s_waitcnt lgkmcnt(0)" ::: "memory");
    __builtin_amdgcn_s_barrier();
}

// 10 consecutive LDS floats (base 16B-aligned)
#define LOAD10(dst, base) do {                                   \
    const float4 _a = *(const float4*)(base);                    \
    const float4 _b = *(const float4*)((base) + 4);              \
    const float2 _c = *(const float2*)((base) + 8);              \
    dst[0]=_a.x; dst[1]=_a.y; dst[2]=_a.z; dst[3]=_a.w;          \
    dst[4]=_b.x; dst[5]=_b.y; dst[6]=_b.z; dst[7]=_b.w;          \
    dst[8]=_c.x; dst[9]=_c.y; } while (0)

// 6 consecutive LDS floats (base 16B-aligned)
#define LOAD6(dst, base) do {                                    \
    const float4 _a = *(const float4*)(base);                    \
    const float2 _c = *(const float2*)((base) + 4);              \
    dst[0]=_a.x; dst[1]=_a.y; dst[2]=_a.z; dst[3]=_a.w;          \
    dst[4]=_c.x; dst[5]=_c.y; } while (0)

__global__ __launch_bounds__(256, 3) void Net_18966575579675_kernel(
    const float* __restrict__ prior, const float* __restrict__ camera,
    const float* __restrict__ W1, const float* __restrict__ b1,
    const float* __restrict__ W2, const float* __restrict__ b2,
    const float* __restrict__ W3, const float* __restrict__ b3,
    float* __restrict__ out)
{
    const int tid  = threadIdx.x;
    const int lane = tid & 63;
    const int wave = __builtin_amdgcn_readfirstlane(tid >> 6);
    const int b0   = blockIdx.x * 256;
    const int g    = blockIdx.y;                 // 4-chunk group
    const int cig  = (g == NG - 1) ? 1 : 4;      // chunks in this group

    __shared__ __align__(16) float wbuf[16 * NETSTRIDE];  // 23552 B
    __shared__ float obuf[64 * OSTRIDE];                  // 24832 B

    // ---- stage this group's weights ONCE (wave-private slots: each wave
    // stages and reads only its own nets -> no barrier, in-order LDS) ----
#pragma unroll
    for (int c = 0; c < 4; ++c) {
        if (c < cig) {
            const int ns = g * 16 + c * 4 + wave;
            if (ns < NN) {
                float* wd = wbuf + (c * 4 + wave) * NETSTRIDE;
                const float* s1 = W1 + (size_t)ns * (CAMD + 1) * HD;   // 110
#pragma unroll
                for (int t0 = 0; t0 < 110; t0 += 64) {
                    const int t = t0 + lane;
                    if (t < 110) { const int i = t / 10, j = t - 10 * i; wd[i * 12 + j] = s1[t]; }
                }
                const float* s2 = W2 + (size_t)ns * HD * HD;           // 100
#pragma unroll
                for (int t0 = 0; t0 < 100; t0 += 64) {
                    const int t = t0 + lane;
                    if (t < 100) { const int j = t / 10, k = t - 10 * j; wd[OFF_W2 + j * 12 + k] = s2[t]; }
                }
                const float* s3 = W3 + (size_t)ns * HD * LODD;         // 60
                if (lane < 60) { const int j = lane / 6, m = lane - 6 * j; wd[OFF_W3 + j * 8 + m] = s3[lane]; }
                if (lane < 10)      wd[OFF_B1 + lane]      = b1[(size_t)ns * HD + lane];
                else if (lane < 20) wd[OFF_B2 + lane - 10] = b2[(size_t)ns * HD + lane - 10];
                else if (lane < 26) wd[OFF_B3 + lane - 20] = b3[(size_t)ns * LODD + lane - 20];
            }
        }
    }

    // ---- prior prefetch for phase (q=0, c=0) ----
    float prC0, prC1;
    {
        const int n0 = g * 16 + wave;
        const int nc = n0 < NN ? n0 : NN - 1;
        prC0 = prior[(size_t)(b0 + lane) * NN + nc];
        prC1 = prior[(size_t)(b0 + 64 + lane) * NN + nc];
    }

#pragma unroll 1
    for (int q = 0; q < 2; ++q) {        // two 128-row halves
        // camera for this half's two sub-rows -> registers
        float camA[CAMD], camB[CAMD];
        {
            const float2* ca = (const float2*)(camera + (size_t)(b0 + q * 128 + lane) * CAMD);
            const float2* cb = (const float2*)(camera + (size_t)(b0 + q * 128 + 64 + lane) * CAMD);
#pragma unroll
            for (int i = 0; i < CAMD / 2; ++i) {
                const float2 va = ca[i];
                const float2 vb = cb[i];
                camA[2 * i] = va.x; camA[2 * i + 1] = va.y;
                camB[2 * i] = vb.x; camB[2 * i + 1] = vb.y;
            }
        }

        float o2[4][LODD];   // s=1 rows parked until second flush pass

#pragma unroll
        for (int c = 0; c < 4; ++c) {
            if (c < cig) {
                const int n   = g * 16 + c * 4 + wave;
                const bool act = (n < NN);

                // prefetch NEXT phase's prior (uniform control flow)
                float nx0 = prC0, nx1 = prC1;
                {
                    int nq = q, nc = c + 1;
                    bool have = true;
                    if (nc >= cig) { nc = 0; nq = q + 1; have = (nq < 2); }
                    if (have) {
                        const int nn2 = g * 16 + nc * 4 + wave;
                        const int nnc = nn2 < NN ? nn2 : NN - 1;
                        nx0 = prior[(size_t)(b0 + nq * 128 + lane) * NN + nnc];
                        nx1 = prior[(size_t)(b0 + nq * 128 + 64 + lane) * NN + nnc];
                    }
                }

                if (act) {
                    const float* wb = wbuf + (c * 4 + wave) * NETSTRIDE;

                    // ---- layer 1 (2 rows) ----
                    float h1[2][HD];
                    {
                        float bv[10]; LOAD10(bv, wb + OFF_B1);
                        float wv[10]; LOAD10(wv, wb);          // W1 row 0
#pragma unroll
                        for (int j = 0; j < HD; ++j) {
                            h1[0][j] = fmaf(prC0, wv[j], bv[j]);
                            h1[1][j] = fmaf(prC1, wv[j], bv[j]);
                        }
                    }
#pragma unroll
                    for (int i2 = 0; i2 < CAMD / 2; ++i2) {
                        float wa[10]; LOAD10(wa, wb + (2 * i2 + 1) * 12);
                        float wc[10]; LOAD10(wc, wb + (2 * i2 + 2) * 12);
#pragma unroll
                        for (int j = 0; j < HD; ++j) {
                            h1[0][j] = fmaf(camA[2 * i2], wa[j], h1[0][j]);
                            h1[1][j] = fmaf(camB[2 * i2], wa[j], h1[1][j]);
                        }
#pragma unroll
                        for (int j = 0; j < HD; ++j) {
                            h1[0][j] = fmaf(camA[2 * i2 + 1], wc[j], h1[0][j]);
                            h1[1][j] = fmaf(camB[2 * i2 + 1], wc[j], h1[1][j]);
                        }
                    }
#pragma unroll
                    for (int j = 0; j < HD; ++j) {
                        h1[0][j] = fmaxf(h1[0][j], 0.0f);
                        h1[1][j] = fmaxf(h1[1][j], 0.0f);
                    }

                    // ---- layer 2 ----
                    float h2[2][HD];
                    {
                        float bv[10]; LOAD10(bv, wb + OFF_B2);
#pragma unroll
                        for (int k = 0; k < HD; ++k) { h2[0][k] = bv[k]; h2[1][k] = bv[k]; }
                    }
#pragma unroll
                    for (int j = 0; j < HD; ++j) {
                        float wv[10]; LOAD10(wv, wb + OFF_W2 + j * 12);
#pragma unroll
                        for (int k = 0; k < HD; ++k) {
                            h2[0][k] = fmaf(h1[0][j], wv[k], h2[0][k]);
                            h2[1][k] = fmaf(h1[1][j], wv[k], h2[1][k]);
                        }
                    }
#pragma unroll
                    for (int k = 0; k < HD; ++k) {
                        h2[0][k] = fmaxf(h2[0][k], 0.0f);
                        h2[1][k] = fmaxf(h2[1][k], 0.0f);
                    }

                    // ---- layer 3 ----
                    float o[2][LODD];
                    {
                        float bv[6]; LOAD6(bv, wb + OFF_B3);
#pragma unroll
                        for (int m = 0; m < LODD; ++m) { o[0][m] = bv[m]; o[1][m] = bv[m]; }
                    }
#pragma unroll
                    for (int j = 0; j < HD; ++j) {
                        float wv[6]; LOAD6(wv, wb + OFF_W3 + j * 8);
#pragma unroll
                        for (int m = 0; m < LODD; ++m) {
                            o[0][m] = fmaf(h2[0][j], wv[m], o[0][m]);
                            o[1][m] = fmaf(h2[1][j], wv[m], o[1][m]);
                        }
                    }

                    // stash s=0 row now; park s=1 row in regs
#pragma unroll
                    for (int m = 0; m < LODD; ++m) {
                        obuf[lane * OSTRIDE + c * 24 + wave * LODD + m] = o[0][m];
                        o2[c][m] = o[1][m];
                    }
                }
                prC0 = nx0; prC1 = nx1;
            }
        }

        // ---- flush pass h=0 (rows q*128 + 0..63), 384-B runs ----
        lds_barrier();
        if (g < NG - 1) {
            for (int f = tid; f < 64 * 24; f += 256) {
                const int row  = f / 24;                 // compile-time div
                const int colq = f - row * 24;
                const float* sp = obuf + row * OSTRIDE + colq * 4;
                float4 v = make_float4(sp[0], sp[1], sp[2], sp[3]);
                *(float4*)(out + (size_t)(b0 + q * 128 + row) * ROWF
                           + g * 96 + colq * 4) = v;
            }
        } else {      // tail: 1 chunk, 2 valid nets -> 12 floats/row
            for (int f = tid; f < 64 * 3; f += 256) {
                const int row  = f / 3;
                const int colq = f - row * 3;
                const float* sp = obuf + row * OSTRIDE + colq * 4;
                float4 v = make_float4(sp[0], sp[1], sp[2], sp[3]);
                *(float4*)(out + (size_t)(b0 + q * 128 + row) * ROWF
                           + g * 96 + colq * 4) = v;
            }
        }
        lds_barrier();   // flush reads done -> obuf reusable

        // ---- stash s=1 rows from parked regs ----
#pragma unroll
        for (int c = 0; c < 4; ++c) {
            if (c < cig) {
                const int n = g * 16 + c * 4 + wave;
                if (n < NN) {
#pragma unroll
                    for (int m = 0; m < LODD; ++m)
                        obuf[lane * OSTRIDE + c * 24 + wave * LODD + m] = o2[c][m];
                }
            }
        }

        // ---- flush pass h=1 (rows q*128 + 64..127) ----
        lds_barrier();
        if (g < NG - 1) {
            for (int f = tid; f < 64 * 24; f += 256) {
                const int row  = f / 24;
                const int colq = f - row * 24;
                const float* sp = obuf + row * OSTRIDE + colq * 4;
                float4 v = make_float4(sp[0], sp[1], sp[2], sp[3]);
                *(float4*)(out + (size_t)(b0 + q * 128 + 64 + row) * ROWF
                           + g * 96 + colq * 4) = v;
            }
        } else {
            for (int f = tid; f < 64 * 3; f += 256) {
                const int row  = f / 3;
                const int colq = f - row * 3;
                const float* sp = obuf + row * OSTRIDE + colq * 4;
                float4 v = make_float4(sp[0], sp[1], sp[2], sp[3]);
                *(float4*)(out + (size_t)(b0 + q * 128 + 64 + row) * ROWF
                           + g * 96 + colq * 4) = v;
            }
        }
        lds_barrier();   // obuf reusable for next q
    }
}

extern "C" void kernel_launch(void* const* d_in, const int* in_sizes, int n_in,
                              void* d_out, int out_size, void* d_ws, size_t ws_size,
                              hipStream_t stream) {
    const float* prior  = (const float*)d_in[0];
    const float* camera = (const float*)d_in[1];
    const float* W1     = (const float*)d_in[2];
    const float* b1     = (const float*)d_in[3];
    const float* W2     = (const float*)d_in[4];
    const float* b2     = (const float*)d_in[5];
    const float* W3     = (const float*)d_in[6];
    const float* b3     = (const float*)d_in[7];
    float* out = (float*)d_out;

    dim3 grid(8192 / 256, NG);   // 32 x 46 = 1472 blocks
    dim3 block(256);
    Net_18966575579675_kernel<<<grid, block, 0, stream>>>(
        prior, camera, W1, b1, W2, b2, W3, b3, out);
}